// Round 4
// baseline (376.292 us; speedup 1.0000x reference)
//
#include <hip/hip_runtime.h>
#include <hip/hip_bf16.h>

typedef __bf16 bf16x8 __attribute__((ext_vector_type(8)));
typedef float  f32x4  __attribute__((ext_vector_type(4)));

#define SIZE_  131072
#define DIM_   128
#define BATCH_ 1024
#define KNN_   16

#define BM 64   // emb rows per block
#define BN 64   // bank rows per block (B-panel)
#define MT (BATCH_ / BM)      // 16 m-tiles
#define NP (SIZE_ / BN)       // 2048 n-panels

// ---------------- prep: emb -> bf16 + e_sq ----------------
__global__ __launch_bounds__(256) void prep_emb(const float* __restrict__ emb,
                                                __bf16* __restrict__ emb16,
                                                float* __restrict__ e_sq) {
    int wid  = (blockIdx.x * 256 + threadIdx.x) >> 6;   // row 0..1023
    int lane = threadIdx.x & 63;
    float2 v = *reinterpret_cast<const float2*>(emb + (size_t)wid * DIM_ + lane * 2);
    float s = v.x * v.x + v.y * v.y;
    #pragma unroll
    for (int off = 32; off; off >>= 1) s += __shfl_xor(s, off);
    union { __bf16 h[2]; unsigned int u; } pk;
    pk.h[0] = (__bf16)v.x; pk.h[1] = (__bf16)v.y;
    *reinterpret_cast<unsigned int*>(emb16 + (size_t)wid * DIM_ + lane * 2) = pk.u;
    if (lane == 0) e_sq[wid] = s;
}

// ---------------- fused: B stage + copy + b_sq + GEMM + distance ----------------
// 64x64 tile, A in registers (4 x bf16x8 per wave), B in 16KB swizzled LDS.
// mt==0 blocks additionally write the bank copy (bank read from HBM once).
__global__ __launch_bounds__(256, 4) void gemm_fused(const float* __restrict__ bank,
                                                     const __bf16* __restrict__ emb16,
                                                     const float* __restrict__ e_sq,
                                                     float* __restrict__ out_dist,
                                                     float* __restrict__ out_dots,
                                                     float* __restrict__ out_bank) {
    __shared__ __bf16 lB[BN * DIM_];    // 16 KB, XOR-swizzled rows
    __shared__ float  bsq[BN];
    char* lBc = (char*)lB;

    // XCD-chunked swizzle, mt fastest: 16 consecutive blocks on an XCD share a B-panel.
    int bid     = blockIdx.x;                       // 32768 blocks, %8==0
    int logical = (bid & 7) * (32768 / 8) + (bid >> 3);
    int mt = logical & (MT - 1);
    int np = logical >> 4;
    int m0 = mt * BM;
    int n0 = np * BN;
    int tid  = threadIdx.x;
    int wv   = tid >> 6;
    int lane = tid & 63;
    int lr   = lane & 15;
    int rgrp = lane >> 4;
    int lkb  = rgrp * 8;

    // ---- A fragments: 16 rows x K=128 per wave, held in registers ----
    bf16x8 af[4];
    {
        const __bf16* abase = emb16 + (size_t)(m0 + wv * 16 + lr) * DIM_ + lkb;
        #pragma unroll
        for (int ks = 0; ks < 4; ++ks)
            af[ks] = *reinterpret_cast<const bf16x8*>(abase + ks * 32);
    }

    // ---- stage B panel: read f32 bank rows once; bf16 LDS + b_sq (+ copy if mt==0) ----
    #pragma unroll
    for (int i = 0; i < 8; ++i) {
        int p   = i * 256 + tid;          // 0..2047 float4-chunks
        int row = p >> 5;                 // 32 chunks per row
        int c4  = p & 31;
        size_t gb = (size_t)(n0 + row) * DIM_ + c4 * 4;
        f32x4 v = *reinterpret_cast<const f32x4*>(bank + gb);
        if (mt == 0)
            __builtin_nontemporal_store(v, reinterpret_cast<f32x4*>(out_bank + gb));
        float s = v.x * v.x + v.y * v.y + v.z * v.z + v.w * v.w;
        #pragma unroll
        for (int off = 16; off; off >>= 1) s += __shfl_xor(s, off);   // per-row (32-lane) reduce
        if (c4 == 0) bsq[row] = s;
        union { __bf16 h[4]; unsigned long long u; } pk;
        pk.h[0] = (__bf16)v.x; pk.h[1] = (__bf16)v.y;
        pk.h[2] = (__bf16)v.z; pk.h[3] = (__bf16)v.w;
        int o  = (row << 8) + c4 * 8;
        int so = o ^ ((row & 7) << 4);
        *reinterpret_cast<unsigned long long*>(lBc + so) = pk.u;
    }
    __syncthreads();

    // ---- K-loop: 16 MFMA, B from LDS ----
    f32x4 acc[4] = {};
    #pragma unroll
    for (int ks = 0; ks < 4; ++ks) {
        int kk = ks * 32 + lkb;
        bf16x8 bf[4];
        #pragma unroll
        for (int nc = 0; nc < 4; ++nc) {
            int row = nc * 16 + lr;
            int o   = (row << 8) + kk * 2;
            bf[nc]  = *reinterpret_cast<const bf16x8*>(lBc + (o ^ ((row & 7) << 4)));
        }
        #pragma unroll
        for (int nc = 0; nc < 4; ++nc)
            acc[nc] = __builtin_amdgcn_mfma_f32_16x16x32_bf16(af[ks], bf[nc], acc[nc], 0, 0, 0);
    }

    // ---- epilogue: dist + dots, nontemporal streaming stores ----
    float bsv[4];
    #pragma unroll
    for (int nc = 0; nc < 4; ++nc) bsv[nc] = bsq[nc * 16 + lr];

    #pragma unroll
    for (int j = 0; j < 4; ++j) {
        int grow = m0 + wv * 16 + rgrp * 4 + j;
        float es = e_sq[grow];
        size_t rb = (size_t)grow * SIZE_;
        #pragma unroll
        for (int nc = 0; nc < 4; ++nc) {
            int gcol = n0 + nc * 16 + lr;
            float d  = acc[nc][j];
            float arg = es + bsv[nc] - 2.0f * d;
            __builtin_nontemporal_store(sqrtf(fmaxf(arg, 0.0f)), out_dist + rb + gcol);
            __builtin_nontemporal_store(d, out_dots + rb + gcol);
        }
    }
}

// ---------------- scatter rows (last occurrence wins) ----------------
__global__ __launch_bounds__(128) void scatter_rows(const float* __restrict__ dmem,
                                                    const int* __restrict__ upd,
                                                    float* __restrict__ newbank) {
    int i = blockIdx.x;
    int idx = upd[i];
    __shared__ int dup;
    if (threadIdx.x == 0) dup = 0;
    __syncthreads();
    for (int j = i + 1 + threadIdx.x; j < BATCH_; j += 128)
        if (upd[j] == idx) dup = 1;
    __syncthreads();
    if (dup) return;
    newbank[(size_t)idx * DIM_ + threadIdx.x] = dmem[(size_t)i * DIM_ + threadIdx.x];
}

// ---------------- knn dots (one wave per (b,k), exact f32) ----------------
__global__ __launch_bounds__(256) void knn_kernel(const float* __restrict__ bank,
                                                  const float* __restrict__ emb,
                                                  const int* __restrict__ idxs,
                                                  float* __restrict__ knn) {
    int wid  = (blockIdx.x * 256 + threadIdx.x) >> 6;  // 0..16383
    int lane = threadIdx.x & 63;
    int b    = wid >> 4;
    int idx  = idxs[wid];
    float2 br = *reinterpret_cast<const float2*>(bank + (size_t)idx * DIM_ + lane * 2);
    float2 er = *reinterpret_cast<const float2*>(emb + (size_t)b * DIM_ + lane * 2);
    float s = br.x * er.x + br.y * er.y;
    #pragma unroll
    for (int off = 32; off; off >>= 1) s += __shfl_xor(s, off);
    if (lane == 0) knn[wid] = s;
}

extern "C" void kernel_launch(void* const* d_in, const int* in_sizes, int n_in,
                              void* d_out, int out_size, void* d_ws, size_t ws_size,
                              hipStream_t stream) {
    const float* emb  = (const float*)d_in[0];
    const float* dmem = (const float*)d_in[1];
    const float* bank = (const float*)d_in[2];
    const int*   idxs = (const int*)d_in[3];
    const int*   upd  = (const int*)d_in[4];

    float* out       = (float*)d_out;
    float* out_dist  = out;
    float* out_dots  = out + (size_t)BATCH_ * SIZE_;
    float* out_knn   = out + (size_t)2 * BATCH_ * SIZE_;
    float* out_bank  = out_knn + (size_t)BATCH_ * KNN_;

    char*   ws    = (char*)d_ws;
    float*  e_sq  = (float*)ws;                        // 1024 f32 = 4 KB
    __bf16* emb16 = (__bf16*)(ws + 4096);              // 1024*128 bf16 = 256 KB

    prep_emb  <<<BATCH_ / 4, 256, 0, stream>>>(emb, emb16, e_sq);
    gemm_fused<<<MT * NP, 256, 0, stream>>>(bank, emb16, e_sq, out_dist, out_dots, out_bank);
    scatter_rows<<<BATCH_, 128, 0, stream>>>(dmem, upd, out_bank);
    knn_kernel<<<(BATCH_ * KNN_) / 4, 256, 0, stream>>>(bank, emb, idxs, out_knn);
}

// Round 5
// 274.822 us; speedup vs baseline: 1.3692x; 1.3692x over previous
//
#include <hip/hip_runtime.h>
#include <hip/hip_bf16.h>

typedef __bf16 bf16x8 __attribute__((ext_vector_type(8)));
typedef float  f32x4  __attribute__((ext_vector_type(4)));

#define SIZE_  131072
#define DIM_   128
#define BATCH_ 1024
#define KNN_   16

#define BM 256
#define BN 64

// ---------------- prep: emb -> bf16 + e_sq ----------------
__global__ __launch_bounds__(256) void prep_emb(const float* __restrict__ emb,
                                                __bf16* __restrict__ emb16,
                                                float* __restrict__ e_sq) {
    int wid  = (blockIdx.x * 256 + threadIdx.x) >> 6;   // row 0..1023
    int lane = threadIdx.x & 63;
    float2 v = *reinterpret_cast<const float2*>(emb + (size_t)wid * DIM_ + lane * 2);
    float s = v.x * v.x + v.y * v.y;
    #pragma unroll
    for (int off = 32; off; off >>= 1) s += __shfl_xor(s, off);
    union { __bf16 h[2]; unsigned int u; } pk;
    pk.h[0] = (__bf16)v.x; pk.h[1] = (__bf16)v.y;
    *reinterpret_cast<unsigned int*>(emb16 + (size_t)wid * DIM_ + lane * 2) = pk.u;
    if (lane == 0) e_sq[wid] = s;
}

// ---------------- prep: bank copy -> new_bank + b_sq ----------------
__global__ __launch_bounds__(256) void prep_bank(const float* __restrict__ bank,
                                                 float* __restrict__ newbank,
                                                 float* __restrict__ b_sq) {
    int wid  = (blockIdx.x * 256 + threadIdx.x) >> 6;   // row 0..131071
    int lane = threadIdx.x & 63;
    size_t base = (size_t)wid * DIM_ + lane * 2;
    float2 v = *reinterpret_cast<const float2*>(bank + base);
    *reinterpret_cast<float2*>(newbank + base) = v;
    float s = v.x * v.x + v.y * v.y;
    #pragma unroll
    for (int off = 32; off; off >>= 1) s += __shfl_xor(s, off);
    if (lane == 0) b_sq[wid] = s;
}

// ---------------- main GEMM + fused distance, LDS-transposed f32x4 writeback ----------------
__global__ __launch_bounds__(256) void gemm_dist(const float* __restrict__ bank,
                                                 const __bf16* __restrict__ emb16,
                                                 const float* __restrict__ e_sq,
                                                 const float* __restrict__ b_sq,
                                                 float* __restrict__ out_dist,
                                                 float* __restrict__ out_dots) {
    __shared__ __bf16 lA[BM * DIM_];   // 64 KB (A tile, reused as f32 out-tile in epilogue)
    __shared__ __bf16 lB[BN * DIM_];   // 16 KB
    char* lAc = (char*)lA;
    char* lBc = (char*)lB;

    // XCD-chunked swizzle, mt fastest: 4 m-tiles share one B-panel on the same XCD
    int bid = blockIdx.x;                      // nwg = 8192, divisible by 8
    int logical = (bid & 7) * (8192 / 8) + (bid >> 3);
    int mt = logical & 3;
    int nt = logical >> 2;
    int m0 = mt * BM;
    int n0 = nt * BN;
    int tid = threadIdx.x;

    // ---- stage A (contiguous bf16 rows from ws) ----
    {
        const char* src = (const char*)(emb16 + (size_t)m0 * DIM_);   // 65536 B
        #pragma unroll
        for (int i = 0; i < 16; ++i) {
            int o   = (i * 256 + tid) * 16;            // byte offset
            int row = o >> 8;                          // 256 B per row
            int so  = o ^ ((row & 7) << 4);
            *reinterpret_cast<int4*>(lAc + so) = *reinterpret_cast<const int4*>(src + o);
        }
    }
    // ---- stage B (f32 bank rows -> bf16, swizzled) ----
    {
        #pragma unroll
        for (int i = 0; i < 4; ++i) {
            int p   = i * 256 + tid;                   // 0..1023, 8 f32 each
            int row = p >> 4;                          // 16 chunks of 8 per row
            int k0  = (p & 15) * 8;
            const f32x4* s4 = reinterpret_cast<const f32x4*>(bank + (size_t)(n0 + row) * DIM_ + k0);
            f32x4 a = s4[0], b = s4[1];
            union { __bf16 h[8]; int4 v; } pk;
            pk.h[0] = (__bf16)a.x; pk.h[1] = (__bf16)a.y; pk.h[2] = (__bf16)a.z; pk.h[3] = (__bf16)a.w;
            pk.h[4] = (__bf16)b.x; pk.h[5] = (__bf16)b.y; pk.h[6] = (__bf16)b.z; pk.h[7] = (__bf16)b.w;
            int o  = (row << 8) + k0 * 2;
            int so = o ^ ((row & 7) << 4);
            *reinterpret_cast<int4*>(lBc + so) = pk.v;
        }
    }
    __syncthreads();

    int wv   = tid >> 6;        // wave 0..3 -> rows wv*64..
    int lane = tid & 63;
    int lr   = lane & 15;       // fragment row/col
    int lkb  = (lane >> 4) * 8; // k sub-offset
    int rgrp = lane >> 4;

    f32x4 acc[4][4] = {};

    #pragma unroll
    for (int ks = 0; ks < 4; ++ks) {
        int kk = ks * 32 + lkb;
        bf16x8 af[4], bf[4];
        #pragma unroll
        for (int mr = 0; mr < 4; ++mr) {
            int row = wv * 64 + mr * 16 + lr;
            int o   = (row << 8) + kk * 2;
            af[mr]  = *reinterpret_cast<const bf16x8*>(lAc + (o ^ ((row & 7) << 4)));
        }
        #pragma unroll
        for (int nc = 0; nc < 4; ++nc) {
            int row = nc * 16 + lr;
            int o   = (row << 8) + kk * 2;
            bf[nc]  = *reinterpret_cast<const bf16x8*>(lBc + (o ^ ((row & 7) << 4)));
        }
        #pragma unroll
        for (int mr = 0; mr < 4; ++mr)
            #pragma unroll
            for (int nc = 0; nc < 4; ++nc)
                acc[mr][nc] = __builtin_amdgcn_mfma_f32_16x16x32_bf16(af[mr], bf[nc], acc[mr][nc], 0, 0, 0);
    }

    // ---- epilogue: LDS transpose -> f32x4 contiguous nontemporal stores ----
    float bs[4];
    #pragma unroll
    for (int nc = 0; nc < 4; ++nc) bs[nc] = b_sq[n0 + nc * 16 + lr];
    float es[4][4];
    #pragma unroll
    for (int mr = 0; mr < 4; ++mr)
        #pragma unroll
        for (int j = 0; j < 4; ++j)
            es[mr][j] = e_sq[m0 + wv * 64 + mr * 16 + rgrp * 4 + j];

    __syncthreads();                       // all waves done reading lA
    char* ftile = lAc;                     // 256 rows x 64 cols f32 = 64 KB

    #pragma unroll
    for (int pass = 0; pass < 2; ++pass) {
        // scatter acc (+distance transform) into LDS tile, swizzled
        #pragma unroll
        for (int mr = 0; mr < 4; ++mr) {
            #pragma unroll
            for (int j = 0; j < 4; ++j) {
                int row = wv * 64 + mr * 16 + rgrp * 4 + j;
                #pragma unroll
                for (int nc = 0; nc < 4; ++nc) {
                    float d = acc[mr][nc][j];
                    float val;
                    if (pass == 0) {
                        float arg = es[mr][j] + bs[nc] - 2.0f * d;
                        val = sqrtf(fmaxf(arg, 0.0f));
                    } else {
                        val = d;
                    }
                    int o = (row << 8) + (nc * 16 + lr) * 4;
                    *reinterpret_cast<float*>(ftile + (o ^ ((row & 7) << 4))) = val;
                }
            }
        }
        __syncthreads();
        // linear readback: each wave-store = 4 rows x 256B contiguous
        float* outp = pass ? out_dots : out_dist;
        int g  = tid >> 4;                 // 0..15
        int c4 = tid & 15;                 // 0..15 -> 16B column chunk
        #pragma unroll
        for (int i = 0; i < 16; ++i) {
            int row = i * 16 + g;
            int o   = (row << 8) + c4 * 16;
            f32x4 v = *reinterpret_cast<const f32x4*>(ftile + (o ^ ((row & 7) << 4)));
            size_t ga = (size_t)(m0 + row) * SIZE_ + n0 + c4 * 4;
            __builtin_nontemporal_store(v, reinterpret_cast<f32x4*>(outp + ga));
        }
        __syncthreads();
    }
}

// ---------------- scatter rows (last occurrence wins) ----------------
__global__ __launch_bounds__(128) void scatter_rows(const float* __restrict__ dmem,
                                                    const int* __restrict__ upd,
                                                    float* __restrict__ newbank) {
    int i = blockIdx.x;
    int idx = upd[i];
    __shared__ int dup;
    if (threadIdx.x == 0) dup = 0;
    __syncthreads();
    for (int j = i + 1 + threadIdx.x; j < BATCH_; j += 128)
        if (upd[j] == idx) dup = 1;
    __syncthreads();
    if (dup) return;
    newbank[(size_t)idx * DIM_ + threadIdx.x] = dmem[(size_t)i * DIM_ + threadIdx.x];
}

// ---------------- knn dots (one wave per (b,k), exact f32) ----------------
__global__ __launch_bounds__(256) void knn_kernel(const float* __restrict__ bank,
                                                  const float* __restrict__ emb,
                                                  const int* __restrict__ idxs,
                                                  float* __restrict__ knn) {
    int wid  = (blockIdx.x * 256 + threadIdx.x) >> 6;  // 0..16383
    int lane = threadIdx.x & 63;
    int b    = wid >> 4;
    int idx  = idxs[wid];
    float2 br = *reinterpret_cast<const float2*>(bank + (size_t)idx * DIM_ + lane * 2);
    float2 er = *reinterpret_cast<const float2*>(emb + (size_t)b * DIM_ + lane * 2);
    float s = br.x * er.x + br.y * er.y;
    #pragma unroll
    for (int off = 32; off; off >>= 1) s += __shfl_xor(s, off);
    if (lane == 0) knn[wid] = s;
}

extern "C" void kernel_launch(void* const* d_in, const int* in_sizes, int n_in,
                              void* d_out, int out_size, void* d_ws, size_t ws_size,
                              hipStream_t stream) {
    const float* emb  = (const float*)d_in[0];
    const float* dmem = (const float*)d_in[1];
    const float* bank = (const float*)d_in[2];
    const int*   idxs = (const int*)d_in[3];
    const int*   upd  = (const int*)d_in[4];

    float* out       = (float*)d_out;
    float* out_dist  = out;
    float* out_dots  = out + (size_t)BATCH_ * SIZE_;
    float* out_knn   = out + (size_t)2 * BATCH_ * SIZE_;
    float* out_bank  = out_knn + (size_t)BATCH_ * KNN_;

    char*   ws    = (char*)d_ws;
    float*  b_sq  = (float*)ws;                        // 131072 f32 = 512 KB
    float*  e_sq  = (float*)(ws + 524288);             // 1024 f32
    __bf16* emb16 = (__bf16*)(ws + 528384);            // 1024*128 bf16 = 256 KB

    prep_emb <<<BATCH_ / 4,      256, 0, stream>>>(emb, emb16, e_sq);
    prep_bank<<<SIZE_ / 4,       256, 0, stream>>>(bank, out_bank, b_sq);
    gemm_dist<<<(BATCH_ / BM) * (SIZE_ / BN), 256, 0, stream>>>(bank, emb16, e_sq, b_sq, out_dist, out_dots);
    scatter_rows<<<BATCH_,       128, 0, stream>>>(dmem, upd, out_bank);
    knn_kernel<<<(BATCH_ * KNN_) / 4, 256, 0, stream>>>(bank, emb, idxs, out_knn);
}

// Round 6
// 261.373 us; speedup vs baseline: 1.4397x; 1.0515x over previous
//
#include <hip/hip_runtime.h>
#include <hip/hip_bf16.h>

typedef __bf16 bf16x8 __attribute__((ext_vector_type(8)));
typedef float  f32x4  __attribute__((ext_vector_type(4)));

#define SIZE_  131072
#define DIM_   128
#define BATCH_ 1024
#define KNN_   16

#define BM 128
#define BN 64
#define MT (BATCH_ / BM)          // 8
#define NT (SIZE_ / BN)           // 2048

// ---------------- prep: emb -> bf16 + e_sq ----------------
__global__ __launch_bounds__(256) void prep_emb(const float* __restrict__ emb,
                                                __bf16* __restrict__ emb16,
                                                float* __restrict__ e_sq) {
    int wid  = (blockIdx.x * 256 + threadIdx.x) >> 6;   // row 0..1023
    int lane = threadIdx.x & 63;
    float2 v = *reinterpret_cast<const float2*>(emb + (size_t)wid * DIM_ + lane * 2);
    float s = v.x * v.x + v.y * v.y;
    #pragma unroll
    for (int off = 32; off; off >>= 1) s += __shfl_xor(s, off);
    union { __bf16 h[2]; unsigned int u; } pk;
    pk.h[0] = (__bf16)v.x; pk.h[1] = (__bf16)v.y;
    *reinterpret_cast<unsigned int*>(emb16 + (size_t)wid * DIM_ + lane * 2) = pk.u;
    if (lane == 0) e_sq[wid] = s;
}

// ---------------- GEMM + fused {bank copy, b_sq, distance}, LDS-transposed writeback ----------------
// BM=128 tile: lA 32KB + lB 16KB, ftile reuses lA -> 48KB LDS -> 3 blocks/CU.
// Bank read from HBM exactly once (mt==0 block emits new_bank copy; b_sq computed in-stage).
__global__ __launch_bounds__(256) void gemm_dist(const float* __restrict__ bank,
                                                 const __bf16* __restrict__ emb16,
                                                 const float* __restrict__ e_sq,
                                                 float* __restrict__ out_dist,
                                                 float* __restrict__ out_dots,
                                                 float* __restrict__ out_bank) {
    __shared__ __bf16 lA[BM * DIM_];   // 32 KB (A tile; reused as f32 out-tile in epilogue)
    __shared__ __bf16 lB[BN * DIM_];   // 16 KB
    __shared__ float  bsq[BN];
    char* lAc = (char*)lA;
    char* lBc = (char*)lB;

    // XCD-chunked swizzle, mt fastest: 8 m-tiles share one B-panel on the same XCD
    int bid = blockIdx.x;                      // nwg = 16384, %8==0
    int logical = (bid & 7) * (16384 / 8) + (bid >> 3);
    int mt = logical & (MT - 1);
    int nt = logical >> 3;
    int m0 = mt * BM;
    int n0 = nt * BN;
    int tid = threadIdx.x;

    // ---- stage A (contiguous bf16 rows from ws) ----
    {
        const char* src = (const char*)(emb16 + (size_t)m0 * DIM_);   // 32768 B
        #pragma unroll
        for (int i = 0; i < 8; ++i) {
            int o   = (i * 256 + tid) * 16;            // byte offset
            int row = o >> 8;                          // 256 B per row
            int so  = o ^ ((row & 7) << 4);
            *reinterpret_cast<int4*>(lAc + so) = *reinterpret_cast<const int4*>(src + o);
        }
    }
    // ---- stage B: read f32 bank rows once -> bf16 LDS + b_sq (+ copy if mt==0) ----
    {
        #pragma unroll
        for (int i = 0; i < 4; ++i) {
            int p   = i * 256 + tid;                   // 0..1023, 8 f32 each
            int row = p >> 4;                          // 16 chunks of 8 per row
            int k0  = (p & 15) * 8;
            size_t gb = (size_t)(n0 + row) * DIM_ + k0;
            const f32x4* s4 = reinterpret_cast<const f32x4*>(bank + gb);
            f32x4 a = s4[0], b = s4[1];
            if (mt == 0) {
                __builtin_nontemporal_store(a, reinterpret_cast<f32x4*>(out_bank + gb));
                __builtin_nontemporal_store(b, reinterpret_cast<f32x4*>(out_bank + gb + 4));
            }
            float s = a.x * a.x + a.y * a.y + a.z * a.z + a.w * a.w
                    + b.x * b.x + b.y * b.y + b.z * b.z + b.w * b.w;
            #pragma unroll
            for (int off = 8; off; off >>= 1) s += __shfl_xor(s, off);  // 16-lane row group
            if ((p & 15) == 0) bsq[row] = s;
            union { __bf16 h[8]; int4 v; } pk;
            pk.h[0] = (__bf16)a.x; pk.h[1] = (__bf16)a.y; pk.h[2] = (__bf16)a.z; pk.h[3] = (__bf16)a.w;
            pk.h[4] = (__bf16)b.x; pk.h[5] = (__bf16)b.y; pk.h[6] = (__bf16)b.z; pk.h[7] = (__bf16)b.w;
            int o  = (row << 8) + k0 * 2;
            int so = o ^ ((row & 7) << 4);
            *reinterpret_cast<int4*>(lBc + so) = pk.v;
        }
    }
    __syncthreads();

    int wv   = tid >> 6;        // wave 0..3 -> rows wv*32..
    int lane = tid & 63;
    int lr   = lane & 15;       // fragment row/col
    int lkb  = (lane >> 4) * 8; // k sub-offset
    int rgrp = lane >> 4;

    f32x4 acc[2][4] = {};

    #pragma unroll
    for (int ks = 0; ks < 4; ++ks) {
        int kk = ks * 32 + lkb;
        bf16x8 af[2], bf[4];
        #pragma unroll
        for (int mr = 0; mr < 2; ++mr) {
            int row = wv * 32 + mr * 16 + lr;
            int o   = (row << 8) + kk * 2;
            af[mr]  = *reinterpret_cast<const bf16x8*>(lAc + (o ^ ((row & 7) << 4)));
        }
        #pragma unroll
        for (int nc = 0; nc < 4; ++nc) {
            int row = nc * 16 + lr;
            int o   = (row << 8) + kk * 2;
            bf[nc]  = *reinterpret_cast<const bf16x8*>(lBc + (o ^ ((row & 7) << 4)));
        }
        #pragma unroll
        for (int mr = 0; mr < 2; ++mr)
            #pragma unroll
            for (int nc = 0; nc < 4; ++nc)
                acc[mr][nc] = __builtin_amdgcn_mfma_f32_16x16x32_bf16(af[mr], bf[nc], acc[mr][nc], 0, 0, 0);
    }

    // ---- epilogue: LDS transpose -> f32x4 contiguous nontemporal stores ----
    float bs[4];
    #pragma unroll
    for (int nc = 0; nc < 4; ++nc) bs[nc] = bsq[nc * 16 + lr];
    float es[2][4];
    #pragma unroll
    for (int mr = 0; mr < 2; ++mr)
        #pragma unroll
        for (int j = 0; j < 4; ++j)
            es[mr][j] = e_sq[m0 + wv * 32 + mr * 16 + rgrp * 4 + j];

    __syncthreads();                       // all waves done reading lA
    char* ftile = lAc;                     // 128 rows x 64 cols f32 = 32 KB

    #pragma unroll
    for (int pass = 0; pass < 2; ++pass) {
        #pragma unroll
        for (int mr = 0; mr < 2; ++mr) {
            #pragma unroll
            for (int j = 0; j < 4; ++j) {
                int row = wv * 32 + mr * 16 + rgrp * 4 + j;
                #pragma unroll
                for (int nc = 0; nc < 4; ++nc) {
                    float d = acc[mr][nc][j];
                    float val;
                    if (pass == 0) {
                        float arg = es[mr][j] + bs[nc] - 2.0f * d;
                        val = sqrtf(fmaxf(arg, 0.0f));
                    } else {
                        val = d;
                    }
                    int o = (row << 8) + (nc * 16 + lr) * 4;
                    *reinterpret_cast<float*>(ftile + (o ^ ((row & 7) << 4))) = val;
                }
            }
        }
        __syncthreads();
        // linear readback: each wave-store = 4 rows x 256B contiguous
        float* outp = pass ? out_dots : out_dist;
        int g  = tid >> 4;                 // 0..15
        int c4 = tid & 15;                 // 16B column chunk
        #pragma unroll
        for (int i = 0; i < 8; ++i) {
            int row = i * 16 + g;
            int o   = (row << 8) + c4 * 16;
            f32x4 v = *reinterpret_cast<const f32x4*>(ftile + (o ^ ((row & 7) << 4)));
            size_t ga = (size_t)(m0 + row) * SIZE_ + n0 + c4 * 4;
            __builtin_nontemporal_store(v, reinterpret_cast<f32x4*>(outp + ga));
        }
        __syncthreads();
    }
}

// ---------------- scatter rows (last occurrence wins) ----------------
__global__ __launch_bounds__(128) void scatter_rows(const float* __restrict__ dmem,
                                                    const int* __restrict__ upd,
                                                    float* __restrict__ newbank) {
    int i = blockIdx.x;
    int idx = upd[i];
    __shared__ int dup;
    if (threadIdx.x == 0) dup = 0;
    __syncthreads();
    for (int j = i + 1 + threadIdx.x; j < BATCH_; j += 128)
        if (upd[j] == idx) dup = 1;
    __syncthreads();
    if (dup) return;
    newbank[(size_t)idx * DIM_ + threadIdx.x] = dmem[(size_t)i * DIM_ + threadIdx.x];
}

// ---------------- knn dots (one wave per (b,k), exact f32) ----------------
__global__ __launch_bounds__(256) void knn_kernel(const float* __restrict__ bank,
                                                  const float* __restrict__ emb,
                                                  const int* __restrict__ idxs,
                                                  float* __restrict__ knn) {
    int wid  = (blockIdx.x * 256 + threadIdx.x) >> 6;  // 0..16383
    int lane = threadIdx.x & 63;
    int b    = wid >> 4;
    int idx  = idxs[wid];
    float2 br = *reinterpret_cast<const float2*>(bank + (size_t)idx * DIM_ + lane * 2);
    float2 er = *reinterpret_cast<const float2*>(emb + (size_t)b * DIM_ + lane * 2);
    float s = br.x * er.x + br.y * er.y;
    #pragma unroll
    for (int off = 32; off; off >>= 1) s += __shfl_xor(s, off);
    if (lane == 0) knn[wid] = s;
}

extern "C" void kernel_launch(void* const* d_in, const int* in_sizes, int n_in,
                              void* d_out, int out_size, void* d_ws, size_t ws_size,
                              hipStream_t stream) {
    const float* emb  = (const float*)d_in[0];
    const float* dmem = (const float*)d_in[1];
    const float* bank = (const float*)d_in[2];
    const int*   idxs = (const int*)d_in[3];
    const int*   upd  = (const int*)d_in[4];

    float* out       = (float*)d_out;
    float* out_dist  = out;
    float* out_dots  = out + (size_t)BATCH_ * SIZE_;
    float* out_knn   = out + (size_t)2 * BATCH_ * SIZE_;
    float* out_bank  = out_knn + (size_t)BATCH_ * KNN_;

    char*   ws    = (char*)d_ws;
    float*  e_sq  = (float*)ws;                        // 1024 f32 = 4 KB
    __bf16* emb16 = (__bf16*)(ws + 4096);              // 1024*128 bf16 = 256 KB

    prep_emb <<<BATCH_ / 4, 256, 0, stream>>>(emb, emb16, e_sq);
    gemm_dist<<<MT * NT,    256, 0, stream>>>(bank, emb16, e_sq, out_dist, out_dots, out_bank);
    scatter_rows<<<BATCH_,  128, 0, stream>>>(dmem, upd, out_bank);
    knn_kernel<<<(BATCH_ * KNN_) / 4, 256, 0, stream>>>(bank, emb, idxs, out_knn);
}

// Round 7
// 258.137 us; speedup vs baseline: 1.4577x; 1.0125x over previous
//
#include <hip/hip_runtime.h>
#include <hip/hip_bf16.h>

typedef __bf16 bf16x8 __attribute__((ext_vector_type(8)));
typedef float  f32x4  __attribute__((ext_vector_type(4)));

#define SIZE_  131072
#define DIM_   128
#define BATCH_ 1024
#define KNN_   16

#define BM 64
#define BN 64
#define MT (BATCH_ / BM)          // 16
#define NT (SIZE_ / BN)           // 2048
#define NWG (MT * NT)             // 32768

// ---------------- prep: emb -> bf16 + e_sq ----------------
__global__ __launch_bounds__(256) void prep_emb(const float* __restrict__ emb,
                                                __bf16* __restrict__ emb16,
                                                float* __restrict__ e_sq) {
    int wid  = (blockIdx.x * 256 + threadIdx.x) >> 6;   // row 0..1023
    int lane = threadIdx.x & 63;
    float2 v = *reinterpret_cast<const float2*>(emb + (size_t)wid * DIM_ + lane * 2);
    float s = v.x * v.x + v.y * v.y;
    #pragma unroll
    for (int off = 32; off; off >>= 1) s += __shfl_xor(s, off);
    union { __bf16 h[2]; unsigned int u; } pk;
    pk.h[0] = (__bf16)v.x; pk.h[1] = (__bf16)v.y;
    *reinterpret_cast<unsigned int*>(emb16 + (size_t)wid * DIM_ + lane * 2) = pk.u;
    if (lane == 0) e_sq[wid] = s;
}

// ---------------- GEMM + fused {bank copy, b_sq, distance, knn} ----------------
// 64x64 tile, A in registers, B in 16KB swizzled LDS; unified 32KB ftile
// (dist+dots) overlapping lB -> 33KB LDS -> 4 blocks/CU; 3 barriers total.
// Bank leaves HBM exactly once (mt==0 block emits new_bank copy).
// Blocks 0..4095 additionally compute one knn wave-dot each before staging.
__global__ __launch_bounds__(256) void gemm_dist(const float* __restrict__ bank,
                                                 const __bf16* __restrict__ emb16,
                                                 const float* __restrict__ e_sq,
                                                 const float* __restrict__ emb,
                                                 const int* __restrict__ idxs,
                                                 float* __restrict__ out_dist,
                                                 float* __restrict__ out_dots,
                                                 float* __restrict__ out_bank,
                                                 float* __restrict__ out_knn) {
    __shared__ alignas(16) char smem[33024];
    char*  lBc   = smem;                       // [0, 16384) bf16 B-tile (swizzled)
    char*  ftile = smem;                       // [0, 32768) f32 out-tiles: dist | dots
    float* bsq   = (float*)(smem + 32768);     // [32768, 33024)

    int bid  = blockIdx.x;
    int tid  = threadIdx.x;
    int wv   = tid >> 6;
    int lane = tid & 63;

    // ---- folded knn: first 4096 blocks, one (b,k) pair per wave ----
    if (bid < (BATCH_ * KNN_) / 4) {
        int wid = bid * 4 + wv;
        int b   = wid >> 4;
        int idx = idxs[wid];
        float2 br = *reinterpret_cast<const float2*>(bank + (size_t)idx * DIM_ + lane * 2);
        float2 er = *reinterpret_cast<const float2*>(emb + (size_t)b * DIM_ + lane * 2);
        float s = br.x * er.x + br.y * er.y;
        #pragma unroll
        for (int off = 32; off; off >>= 1) s += __shfl_xor(s, off);
        if (lane == 0) out_knn[wid] = s;
    }

    // XCD-chunked swizzle, mt fastest: 16 m-tiles share one B-panel on one XCD
    int logical = (bid & 7) * (NWG / 8) + (bid >> 3);
    int mt = logical & (MT - 1);
    int nt = logical >> 4;
    int m0 = mt * BM;
    int n0 = nt * BN;

    int lr   = lane & 15;       // fragment row/col
    int rgrp = lane >> 4;
    int lkb  = rgrp * 8;        // k sub-offset

    // ---- A fragments: 16 rows x K=128 per wave, registers (L2-hot emb16) ----
    bf16x8 af[4];
    {
        const __bf16* abase = emb16 + (size_t)(m0 + wv * 16 + lr) * DIM_ + lkb;
        #pragma unroll
        for (int ks = 0; ks < 4; ++ks)
            af[ks] = *reinterpret_cast<const bf16x8*>(abase + ks * 32);
    }

    // ---- stage B: read f32 bank rows once -> bf16 LDS + b_sq (+ copy if mt==0) ----
    #pragma unroll
    for (int i = 0; i < 4; ++i) {
        int p   = i * 256 + tid;                   // 0..1023, 8 f32 each
        int row = p >> 4;                          // 64 rows, 16 chunks each
        int k0  = (p & 15) * 8;
        size_t gb = (size_t)(n0 + row) * DIM_ + k0;
        const f32x4* s4 = reinterpret_cast<const f32x4*>(bank + gb);
        f32x4 a = s4[0], b = s4[1];
        if (mt == 0) {
            __builtin_nontemporal_store(a, reinterpret_cast<f32x4*>(out_bank + gb));
            __builtin_nontemporal_store(b, reinterpret_cast<f32x4*>(out_bank + gb + 4));
        }
        float s = a.x * a.x + a.y * a.y + a.z * a.z + a.w * a.w
                + b.x * b.x + b.y * b.y + b.z * b.z + b.w * b.w;
        #pragma unroll
        for (int off = 8; off; off >>= 1) s += __shfl_xor(s, off);  // 16-lane row group
        if ((p & 15) == 0) bsq[row] = s;
        union { __bf16 h[8]; int4 v; } pk;
        pk.h[0] = (__bf16)a.x; pk.h[1] = (__bf16)a.y; pk.h[2] = (__bf16)a.z; pk.h[3] = (__bf16)a.w;
        pk.h[4] = (__bf16)b.x; pk.h[5] = (__bf16)b.y; pk.h[6] = (__bf16)b.z; pk.h[7] = (__bf16)b.w;
        int o  = (row << 8) + k0 * 2;
        int so = o ^ ((row & 7) << 4);
        *reinterpret_cast<int4*>(lBc + so) = pk.v;
    }
    __syncthreads();                                         // barrier 1

    // ---- K-loop: 16 MFMA per wave ----
    f32x4 acc[4] = {};
    #pragma unroll
    for (int ks = 0; ks < 4; ++ks) {
        int kk = ks * 32 + lkb;
        bf16x8 bf[4];
        #pragma unroll
        for (int nc = 0; nc < 4; ++nc) {
            int row = nc * 16 + lr;
            int o   = (row << 8) + kk * 2;
            bf[nc]  = *reinterpret_cast<const bf16x8*>(lBc + (o ^ ((row & 7) << 4)));
        }
        #pragma unroll
        for (int nc = 0; nc < 4; ++nc)
            acc[nc] = __builtin_amdgcn_mfma_f32_16x16x32_bf16(af[ks], bf[nc], acc[nc], 0, 0, 0);
    }

    // ---- epilogue: scalars, then one scatter + one burst writeback ----
    float bs[4];
    #pragma unroll
    for (int nc = 0; nc < 4; ++nc) bs[nc] = bsq[nc * 16 + lr];
    float es[4];
    #pragma unroll
    for (int j = 0; j < 4; ++j) es[j] = e_sq[m0 + wv * 16 + rgrp * 4 + j];

    __syncthreads();                                         // barrier 2 (lB free)

    #pragma unroll
    for (int j = 0; j < 4; ++j) {
        int row = wv * 16 + rgrp * 4 + j;                    // local row 0..63
        int sw  = (row & 7) << 4;
        #pragma unroll
        for (int nc = 0; nc < 4; ++nc) {
            float d   = acc[nc][j];
            float arg = es[j] + bs[nc] - 2.0f * d;
            int o = (row << 8) + (nc * 16 + lr) * 4;
            *reinterpret_cast<float*>(ftile + (o ^ sw))         = sqrtf(fmaxf(arg, 0.0f));
            *reinterpret_cast<float*>(ftile + 16384 + (o ^ sw)) = d;
        }
    }
    __syncthreads();                                         // barrier 3

    // burst writeback: 8 x 16B per thread, both outputs
    #pragma unroll
    for (int i = 0; i < 8; ++i) {
        int p    = i * 256 + tid;          // 0..2047 16B-chunks over 32KB
        int half = p >> 10;                // 0 = dist, 1 = dots
        int pr   = p & 1023;
        int row  = pr >> 4;
        int c4   = pr & 15;
        int o    = (row << 8) + c4 * 16;
        f32x4 v = *reinterpret_cast<const f32x4*>(ftile + half * 16384 + (o ^ ((row & 7) << 4)));
        size_t ga = (size_t)(m0 + row) * SIZE_ + n0 + c4 * 4;
        float* outp = half ? out_dots : out_dist;
        __builtin_nontemporal_store(v, reinterpret_cast<f32x4*>(outp + ga));
    }
}

// ---------------- scatter rows (last occurrence wins) ----------------
__global__ __launch_bounds__(128) void scatter_rows(const float* __restrict__ dmem,
                                                    const int* __restrict__ upd,
                                                    float* __restrict__ newbank) {
    int i = blockIdx.x;
    int idx = upd[i];
    __shared__ int dup;
    if (threadIdx.x == 0) dup = 0;
    __syncthreads();
    for (int j = i + 1 + threadIdx.x; j < BATCH_; j += 128)
        if (upd[j] == idx) dup = 1;
    __syncthreads();
    if (dup) return;
    newbank[(size_t)idx * DIM_ + threadIdx.x] = dmem[(size_t)i * DIM_ + threadIdx.x];
}

extern "C" void kernel_launch(void* const* d_in, const int* in_sizes, int n_in,
                              void* d_out, int out_size, void* d_ws, size_t ws_size,
                              hipStream_t stream) {
    const float* emb  = (const float*)d_in[0];
    const float* dmem = (const float*)d_in[1];
    const float* bank = (const float*)d_in[2];
    const int*   idxs = (const int*)d_in[3];
    const int*   upd  = (const int*)d_in[4];

    float* out       = (float*)d_out;
    float* out_dist  = out;
    float* out_dots  = out + (size_t)BATCH_ * SIZE_;
    float* out_knn   = out + (size_t)2 * BATCH_ * SIZE_;
    float* out_bank  = out_knn + (size_t)BATCH_ * KNN_;

    char*   ws    = (char*)d_ws;
    float*  e_sq  = (float*)ws;                        // 1024 f32 = 4 KB
    __bf16* emb16 = (__bf16*)(ws + 4096);              // 1024*128 bf16 = 256 KB

    prep_emb <<<BATCH_ / 4, 256, 0, stream>>>(emb, emb16, e_sq);
    gemm_dist<<<NWG,        256, 0, stream>>>(bank, emb16, e_sq, emb, idxs,
                                              out_dist, out_dots, out_bank, out_knn);
    scatter_rows<<<BATCH_,  128, 0, stream>>>(dmem, upd, out_bank);
}